// Round 9
// baseline (141.113 us; speedup 1.0000x reference)
//
#include <hip/hip_runtime.h>

// BlockSparseAttention B=2,H=16,N=2048,D=64 fp32, block-causal.
// R14 = R13 resubmitted byte-for-byte (acquisition timeout in R8; unmeasured).
// R13: fused single-kernel, TWO fixes from R12's measured 64us dispatch:
//  (1) loop order {barrier; stage_load(i+1); proc(i); stage_write(i+1)} --
//      R12 issued loads right before the barrier; vmcnt(0) drain at every
//      __syncthreads() made each iter pay full uncovered load latency.
//  (2) grid 1024, 4 WGs/CU (R5's verified 64-row q-tile schedule, 72 tiles/CU):
//      R12 counters (Occ 14%, Mfma 12%, VALU 23%, HBM 8%, conflicts 0) = pure
//      latency-bound; 16 waves/CU doubles TLP. LDS 33KB x 4 = 132 <= 160KB.
// Numerics bit-identical to R7/R12 (same verified LDS images, same proc math):
//   K-image: u16 idx = key*64 + ((ch + (key&3) + 4*((key>>3)&1))&7)*8 + (d&7)
//   V-image: u16 idx = 4096 + d*64 + (((key>>3) + (d&7))&7)*8 + (key&7)
// Measured: R7 two-kernel total 135.5 (main 45.5); R12 fused total 130.8
// (main ~64); harness fixed overhead ~65us => kernel-side target is the dispatch.
// Predictions: dispatch ~35-45us, total ~100-112us, Occ 25-30%, VGPR<=128.

typedef short bf16x8 __attribute__((ext_vector_type(8)));
typedef float f32x4  __attribute__((ext_vector_type(4)));
typedef unsigned short u16;
typedef u16 u16x8 __attribute__((ext_vector_type(8)));

#define MFMA(A,B,C) __builtin_amdgcn_mfma_f32_16x16x32_bf16((A),(B),(C),0,0,0)

__device__ __forceinline__ u16 f2bf_rne(float f) {
    union { float f; unsigned u; } c; c.f = f;
    unsigned r = c.u + 0x7FFFu + ((c.u >> 16) & 1u);
    return (u16)(r >> 16);
}
__device__ __forceinline__ u16 f2bf_fast(float f) {
    union { float f; unsigned u; } c; c.f = f;
    return (u16)((c.u + 0x8000u) >> 16);
}

// ---- fused main: 1024 WGs, 64 q-rows each, 4 waves x 16 rows ----
__global__ __launch_bounds__(256, 4)
void bsattn_fused(const float* __restrict__ Q, const float* __restrict__ K,
                  const float* __restrict__ V, const float* __restrict__ SC,
                  const int* __restrict__ RS, const int* __restrict__ RE,
                  float* __restrict__ O)
{
    constexpr int N = 2048, D = 64;
    int wg = blockIdx.x;
    int bh = wg & 31;
    // R5-verified static schedule: CU c's 4 resident WGs (wg = c + 256m) sum to
    // 72 key-tiles: qt sets {28,20,8,0}+kk patterns.
    int i0 = wg >> 5, kk = i0 & 7, rr = i0 >> 3;
    int qt = (rr == 0) ? ((kk < 4) ? 28 + kk : 20 + kk)
           : (rr == 1) ? ((kk < 4) ? 20 + kk : 12 + kk)
           : (rr == 2) ? (8 + kk) : kk;
    int q0 = qt << 6;

    int tid = threadIdx.x, wid = tid >> 6, lane = tid & 63;
    int n = lane & 15, g = lane >> 4;

    __shared__ __align__(16) u16 lsm[16384];   // 2 x 16KB tile image buffers
    __shared__ int sbi[8];

    int myrow = q0 + wid * 16 + n;
    int rs_l = RS[myrow], re_l = RE[myrow];
    int w_rs_min = rs_l, w_rs_max = rs_l, w_re_min = re_l, w_re_max = re_l;
    #pragma unroll
    for (int o = 1; o < 16; o <<= 1) {
        w_rs_min = min(w_rs_min, __shfl_xor(w_rs_min, o));
        w_rs_max = max(w_rs_max, __shfl_xor(w_rs_max, o));
        w_re_min = min(w_re_min, __shfl_xor(w_re_min, o));
        w_re_max = max(w_re_max, __shfl_xor(w_re_max, o));
    }
    if (lane == 0) { sbi[wid * 2] = w_rs_min; sbi[wid * 2 + 1] = w_re_max; }

    float sscale = SC[0] * 1.44269504088896340736f;   // exp2 domain

    bf16x8 qf0, qf1;
    {
        const float* qp = Q + ((size_t)bh * N + myrow) * D + g * 8;
        float4 a0 = *(const float4*)qp,        a1 = *(const float4*)(qp + 4);
        float4 b0 = *(const float4*)(qp + 32), b1 = *(const float4*)(qp + 36);
        qf0[0]=f2bf_rne(a0.x*sscale); qf0[1]=f2bf_rne(a0.y*sscale);
        qf0[2]=f2bf_rne(a0.z*sscale); qf0[3]=f2bf_rne(a0.w*sscale);
        qf0[4]=f2bf_rne(a1.x*sscale); qf0[5]=f2bf_rne(a1.y*sscale);
        qf0[6]=f2bf_rne(a1.z*sscale); qf0[7]=f2bf_rne(a1.w*sscale);
        qf1[0]=f2bf_rne(b0.x*sscale); qf1[1]=f2bf_rne(b0.y*sscale);
        qf1[2]=f2bf_rne(b0.z*sscale); qf1[3]=f2bf_rne(b0.w*sscale);
        qf1[4]=f2bf_rne(b1.x*sscale); qf1[5]=f2bf_rne(b1.y*sscale);
        qf1[6]=f2bf_rne(b1.z*sscale); qf1[7]=f2bf_rne(b1.w*sscale);
    }

    __syncthreads();
    int kst  = min(min(sbi[0], sbi[2]), min(sbi[4], sbi[6])) & ~63;
    int kend = max(max(sbi[1], sbi[3]), max(sbi[5], sbi[7]));
    int t0 = kst >> 6;
    int w  = (kend - kst + 63) >> 6;

    // loop-invariant LDS read offsets (u16 indices; verified images)
    int rA   = ((n >> 2) << 3) + (n & 3);
    int phk  = (n & 3) + 4 * ((n >> 2) & 1);
    int osA0 = rA * 64 + ((g + phk) & 7) * 8;
    int osA1 = rA * 64 + ((g + 4 + phk) & 7) * 8;
    int ov0  = 4096 + n * 64 + ((    g + (n & 7)) & 7) * 8;
    int ov1  = 4096 + n * 64 + ((4 + g + (n & 7)) & 7) * 8;

    // loop-invariant STAGING coords (formulas identical to the verified prep kernel)
    int key_l = tid >> 2, c2 = (tid & 3) << 1;                 // K: thread -> (key, dim-chunk)
    int rotb  = (key_l & 3) + 4 * ((key_l >> 3) & 1);
    int kiA   = key_l * 64 + (((c2    ) + rotb) & 7) * 8;      // K-image write offsets
    int kiB   = key_l * 64 + (((c2 + 1) + rotb) & 7) * 8;
    int kc    = lane >> 3, kw = lane & 7;                      // V: thread -> (key=lane, dims wid*16..)
    const float* Kb = K + (size_t)bh * N * D;
    const float* Vb = V + (size_t)bh * N * D;

    f32x4 acc[4], accl = {0.f, 0.f, 0.f, 0.f};
    #pragma unroll
    for (int c = 0; c < 4; ++c) acc[c] = (f32x4){0.f, 0.f, 0.f, 0.f};
    bf16x8 ones;
    #pragma unroll
    for (int j = 0; j < 8; ++j) ones[j] = (short)0x3F80;

    // in-flight f32 tile staged in registers (issue after barrier, write after proc)
    float4 kf0, kf1, kf2, kf3, vf0, vf1, vf2, vf3;

    auto stage_load = [&](int i) {          // issue f32 global loads for tile t0+i
        if (i < w) {
            const float* kp = Kb + (size_t)(t0 + i) * 4096 + key_l * 64 + c2 * 8;
            kf0 = *(const float4*)kp;       kf1 = *(const float4*)(kp + 4);
            kf2 = *(const float4*)(kp + 8); kf3 = *(const float4*)(kp + 12);
            const float* vp = Vb + (size_t)(t0 + i) * 4096 + lane * 64 + wid * 16;
            vf0 = *(const float4*)vp;       vf1 = *(const float4*)(vp + 4);
            vf2 = *(const float4*)(vp + 8); vf3 = *(const float4*)(vp + 12);
        }
    };
    auto stage_write = [&](int i) {         // cvt + swizzled LDS image write
        if (i < w) {
            u16* dst = &lsm[(i & 1) << 13];
            u16x8 a, b;
            a[0]=f2bf_rne(kf0.x); a[1]=f2bf_rne(kf0.y); a[2]=f2bf_rne(kf0.z); a[3]=f2bf_rne(kf0.w);
            a[4]=f2bf_rne(kf1.x); a[5]=f2bf_rne(kf1.y); a[6]=f2bf_rne(kf1.z); a[7]=f2bf_rne(kf1.w);
            b[0]=f2bf_rne(kf2.x); b[1]=f2bf_rne(kf2.y); b[2]=f2bf_rne(kf2.z); b[3]=f2bf_rne(kf2.w);
            b[4]=f2bf_rne(kf3.x); b[5]=f2bf_rne(kf3.y); b[6]=f2bf_rne(kf3.z); b[7]=f2bf_rne(kf3.w);
            *(u16x8*)&dst[kiA] = a;
            *(u16x8*)&dst[kiB] = b;
            float vy[16] = { vf0.x,vf0.y,vf0.z,vf0.w, vf1.x,vf1.y,vf1.z,vf1.w,
                             vf2.x,vf2.y,vf2.z,vf2.w, vf3.x,vf3.y,vf3.z,vf3.w };
            #pragma unroll
            for (int j = 0; j < 16; ++j) {
                int d = wid * 16 + j;
                dst[4096 + d * 64 + ((kc + (j & 7)) & 7) * 8 + kw] = f2bf_rne(vy[j]);
            }
        }
    };

    auto proc = [&](int kb, const u16* ls) {
        float sc[16];
        #pragma unroll
        for (int h = 0; h < 2; ++h) {
            int hb = h * 2048;
            f32x4 t0v = {0.f,0.f,0.f,0.f}, t1v = t0v;
            __builtin_amdgcn_s_setprio(1);
            t0v = MFMA(*(const bf16x8*)&ls[hb + osA0],       qf0, t0v);
            t0v = MFMA(*(const bf16x8*)&ls[hb + osA1],       qf1, t0v);
            t1v = MFMA(*(const bf16x8*)&ls[hb + osA0 + 256], qf0, t1v);
            t1v = MFMA(*(const bf16x8*)&ls[hb + osA1 + 256], qf1, t1v);
            __builtin_amdgcn_s_setprio(0);
            #pragma unroll
            for (int r = 0; r < 4; ++r) { sc[h*8 + r] = t0v[r]; sc[h*8 + 4 + r] = t1v[r]; }
        }
        if (kb < w_rs_max || kb + 64 > w_re_min) {      // boundary tiles only
            #pragma unroll
            for (int h = 0; h < 2; ++h)
                #pragma unroll
                for (int j = 0; j < 8; ++j) {
                    int key = kb + h * 32 + g * 8 + j;
                    if (key < rs_l || key >= re_l) sc[h*8 + j] = -1e30f;
                }
        }
        bf16x8 pf0, pf1;
        #pragma unroll
        for (int j = 0; j < 8; ++j) { float p = __builtin_amdgcn_exp2f(sc[j]);     pf0[j] = (short)f2bf_fast(p); }
        #pragma unroll
        for (int j = 0; j < 8; ++j) { float p = __builtin_amdgcn_exp2f(sc[8 + j]); pf1[j] = (short)f2bf_fast(p); }
        #pragma unroll
        for (int h = 0; h < 2; ++h) {
            const bf16x8& pf = h ? pf1 : pf0;
            int ov = h ? ov1 : ov0;
            __builtin_amdgcn_s_setprio(1);
            acc[0] = MFMA(pf, *(const bf16x8*)&ls[ov       ], acc[0]);
            acc[1] = MFMA(pf, *(const bf16x8*)&ls[ov + 1024], acc[1]);
            acc[2] = MFMA(pf, *(const bf16x8*)&ls[ov + 2048], acc[2]);
            acc[3] = MFMA(pf, *(const bf16x8*)&ls[ov + 3072], acc[3]);
            accl   = MFMA(pf, ones, accl);
            __builtin_amdgcn_s_setprio(0);
        }
    };

    // prologue: tile 0 staged serially (once)
    stage_load(0);
    stage_write(0);
    for (int i = 0; i < w; ++i) {
        __syncthreads();          // buf[i&1] image complete; buf[(i+1)&1] free
        stage_load(i + 1);        // loads in flight, covered by proc(i) below
        proc(kst + (i << 6), &lsm[(i & 1) << 13]);
        stage_write(i + 1);       // vmcnt consumed here, before next barrier
    }

    // epilogue: O[q0+wid*16+4g+r][16c+n] = acc[c][r] / accl[r]
    int rb = g << 2;
    int orow = q0 + wid * 16 + rb;
    float* ob = O + ((size_t)bh * N + orow) * D + n;
    #pragma unroll
    for (int r = 0; r < 4; ++r) {
        float li = 1.0f / accl[r];
        float* rp = ob + (size_t)r * D;
        rp[0]  = acc[0][r] * li;
        rp[16] = acc[1][r] * li;
        rp[32] = acc[2][r] * li;
        rp[48] = acc[3][r] * li;
    }
}

extern "C" void kernel_launch(void* const* d_in, const int* in_sizes, int n_in,
                              void* d_out, int out_size, void* d_ws, size_t ws_size,
                              hipStream_t stream) {
    const float* q  = (const float*)d_in[0];
    const float* k  = (const float*)d_in[1];
    const float* v  = (const float*)d_in[2];
    const float* sc = (const float*)d_in[3];
    const int* rs   = (const int*)d_in[4];
    const int* re   = (const int*)d_in[5];
    float* out      = (float*)d_out;

    bsattn_fused<<<dim3(1024), dim3(256), 0, stream>>>(q, k, v, sc, rs, re, out);
}

// Round 11
// 140.430 us; speedup vs baseline: 1.0049x; 1.0049x over previous
//
#include <hip/hip_runtime.h>

// BlockSparseAttention B=2,H=16,N=2048,D=64 fp32, block-causal.
// R16 = R15 resubmitted byte-for-byte (acquisition timeout in R10; unmeasured).
// R15 = R12 shape (grid 512, 128-row q-tiles, 2 frags/wave) + TWO scheduling fixes:
//  (1) EQUAL-W CU PAIRING: R12's {w,34-w} pairing left the w=32 WG solo for 30/32
//      iters (~2us/iter exposed latency; dispatch 64us). R13 measured 4-WG overlap
//      at ~1.0us/iter => overlap works. New map pairs equal-w WGs on each CU:
//      wg/wg+256 same-CU round-robin; both get SAME qsub, bh differing by 16.
//      Critical {32,32} CU dual-overlaps fully; light CUs idle early (dispatch
//      = slowest CU, so wasted throughput on light CUs is irrelevant).
//  (2) load-order fix: {barrier; stage_load(i+1); proc(i); stage_write(i+1)} --
//      loads covered by proc, vmcnt=0 by next barrier (R12 paid it uncovered).
// Numerics bit-identical to R12 (passed, absmax 0.0078): same LDS images, proc.
// Measured: R12 fused 130.8 total / ~64 dispatch (Occ 14, Mfma 12, VALU 23);
// R13 (64-row, 4WG/CU) 141.1 / ~73 (Occ 37) => TLP-chasing falsified.
// Prediction: dispatch 43-52us, total 110-118us; if >=60us => same-CU assumption
// wrong -> next: dynamic atomic work-queue.

typedef short bf16x8 __attribute__((ext_vector_type(8)));
typedef float f32x4  __attribute__((ext_vector_type(4)));
typedef unsigned short u16;
typedef u16 u16x8 __attribute__((ext_vector_type(8)));

#define MFMA(A,B,C) __builtin_amdgcn_mfma_f32_16x16x32_bf16((A),(B),(C),0,0,0)

__device__ __forceinline__ u16 f2bf_rne(float f) {
    union { float f; unsigned u; } c; c.f = f;
    unsigned r = c.u + 0x7FFFu + ((c.u >> 16) & 1u);
    return (u16)(r >> 16);
}
__device__ __forceinline__ u16 f2bf_fast(float f) {
    union { float f; unsigned u; } c; c.f = f;
    return (u16)((c.u + 0x8000u) >> 16);
}

// ---- fused main: 512 WGs, 128 q-rows each, 32 q-rows (2 frags) per wave ----
__global__ __launch_bounds__(256, 2)
void bsattn_fused(const float* __restrict__ Q, const float* __restrict__ K,
                  const float* __restrict__ V, const float* __restrict__ SC,
                  const int* __restrict__ RS, const int* __restrict__ RE,
                  float* __restrict__ O)
{
    constexpr int N = 2048, D = 64;
    int wg = blockIdx.x;
    // equal-w pairing: wg and wg+256 share a CU; both get the SAME qsub, bh
    // differing by 16. Coverage: bh 0..31 x qsub 0..15, each exactly once.
    int bh   = (wg & 15) + ((wg >> 8) << 4);
    int qsub = (wg >> 4) & 15;
    int q0 = qsub << 7;                   // 128-row q tile

    int tid = threadIdx.x, wid = tid >> 6, lane = tid & 63;
    int n = lane & 15, g = lane >> 4;

    __shared__ __align__(16) u16 lsm[16384];   // 2 x 16KB tile buffers
    __shared__ int sbi[8];

    int row0 = q0 + wid * 32 + n;          // fragment A row
    int row1 = row0 + 16;                  // fragment B row
    int rs_l0 = RS[row0], re_l0 = RE[row0];
    int rs_l1 = RS[row1], re_l1 = RE[row1];
    int w_rs_min = min(rs_l0, rs_l1), w_rs_max = max(rs_l0, rs_l1);
    int w_re_min = min(re_l0, re_l1), w_re_max = max(re_l0, re_l1);
    #pragma unroll
    for (int o = 1; o < 16; o <<= 1) {
        w_rs_min = min(w_rs_min, __shfl_xor(w_rs_min, o));
        w_rs_max = max(w_rs_max, __shfl_xor(w_rs_max, o));
        w_re_min = min(w_re_min, __shfl_xor(w_re_min, o));
        w_re_max = max(w_re_max, __shfl_xor(w_re_max, o));
    }
    if (lane == 0) { sbi[wid * 2] = w_rs_min; sbi[wid * 2 + 1] = w_re_max; }

    float sscale = SC[0] * 1.44269504088896340736f;   // exp2 domain

    bf16x8 qA0, qA1, qB0, qB1;
    {
        const float* qp = Q + ((size_t)bh * N + row0) * D + g * 8;
        float4 a0 = *(const float4*)qp,        a1 = *(const float4*)(qp + 4);
        float4 b0 = *(const float4*)(qp + 32), b1 = *(const float4*)(qp + 36);
        qA0[0]=f2bf_rne(a0.x*sscale); qA0[1]=f2bf_rne(a0.y*sscale);
        qA0[2]=f2bf_rne(a0.z*sscale); qA0[3]=f2bf_rne(a0.w*sscale);
        qA0[4]=f2bf_rne(a1.x*sscale); qA0[5]=f2bf_rne(a1.y*sscale);
        qA0[6]=f2bf_rne(a1.z*sscale); qA0[7]=f2bf_rne(a1.w*sscale);
        qA1[0]=f2bf_rne(b0.x*sscale); qA1[1]=f2bf_rne(b0.y*sscale);
        qA1[2]=f2bf_rne(b0.z*sscale); qA1[3]=f2bf_rne(b0.w*sscale);
        qA1[4]=f2bf_rne(b1.x*sscale); qA1[5]=f2bf_rne(b1.y*sscale);
        qA1[6]=f2bf_rne(b1.z*sscale); qA1[7]=f2bf_rne(b1.w*sscale);
    }
    {
        const float* qp = Q + ((size_t)bh * N + row1) * D + g * 8;
        float4 a0 = *(const float4*)qp,        a1 = *(const float4*)(qp + 4);
        float4 b0 = *(const float4*)(qp + 32), b1 = *(const float4*)(qp + 36);
        qB0[0]=f2bf_rne(a0.x*sscale); qB0[1]=f2bf_rne(a0.y*sscale);
        qB0[2]=f2bf_rne(a0.z*sscale); qB0[3]=f2bf_rne(a0.w*sscale);
        qB0[4]=f2bf_rne(a1.x*sscale); qB0[5]=f2bf_rne(a1.y*sscale);
        qB0[6]=f2bf_rne(a1.z*sscale); qB0[7]=f2bf_rne(a1.w*sscale);
        qB1[0]=f2bf_rne(b0.x*sscale); qB1[1]=f2bf_rne(b0.y*sscale);
        qB1[2]=f2bf_rne(b0.z*sscale); qB1[3]=f2bf_rne(b0.w*sscale);
        qB1[4]=f2bf_rne(b1.x*sscale); qB1[5]=f2bf_rne(b1.y*sscale);
        qB1[6]=f2bf_rne(b1.z*sscale); qB1[7]=f2bf_rne(b1.w*sscale);
    }

    __syncthreads();
    int kst  = min(min(sbi[0], sbi[2]), min(sbi[4], sbi[6])) & ~63;
    int kend = max(max(sbi[1], sbi[3]), max(sbi[5], sbi[7]));
    int t0 = kst >> 6;
    int w  = (kend - kst + 63) >> 6;

    // loop-invariant LDS read offsets (u16 indices; verified images)
    int rA   = ((n >> 2) << 3) + (n & 3);
    int phk  = (n & 3) + 4 * ((n >> 2) & 1);
    int osA0 = rA * 64 + ((g + phk) & 7) * 8;
    int osA1 = rA * 64 + ((g + 4 + phk) & 7) * 8;
    int ov0  = 4096 + n * 64 + ((    g + (n & 7)) & 7) * 8;
    int ov1  = 4096 + n * 64 + ((4 + g + (n & 7)) & 7) * 8;

    // loop-invariant STAGING coords (formulas identical to the verified prep kernel)
    int key_l = tid >> 2, c2 = (tid & 3) << 1;                 // K: thread -> (key, dim-chunk)
    int rotb  = (key_l & 3) + 4 * ((key_l >> 3) & 1);
    int kiA   = key_l * 64 + (((c2    ) + rotb) & 7) * 8;      // K-image write offsets
    int kiB   = key_l * 64 + (((c2 + 1) + rotb) & 7) * 8;
    int kc    = lane >> 3, kw = lane & 7;                      // V: thread -> (key=lane, dims wid*16..)
    const float* Kb = K + (size_t)bh * N * D;
    const float* Vb = V + (size_t)bh * N * D;

    f32x4 accA[4], accB[4];
    f32x4 acclA = {0.f,0.f,0.f,0.f}, acclB = {0.f,0.f,0.f,0.f};
    #pragma unroll
    for (int c = 0; c < 4; ++c) {
        accA[c] = (f32x4){0.f,0.f,0.f,0.f};
        accB[c] = (f32x4){0.f,0.f,0.f,0.f};
    }
    bf16x8 ones;
    #pragma unroll
    for (int j = 0; j < 8; ++j) ones[j] = (short)0x3F80;

    // in-flight f32 tile staged in registers (issue after barrier, write after proc)
    float4 kf0, kf1, kf2, kf3, vf0, vf1, vf2, vf3;

    auto stage_load = [&](int i) {          // issue f32 global loads for tile t0+i
        if (i < w) {
            const float* kp = Kb + (size_t)(t0 + i) * 4096 + key_l * 64 + c2 * 8;
            kf0 = *(const float4*)kp;       kf1 = *(const float4*)(kp + 4);
            kf2 = *(const float4*)(kp + 8); kf3 = *(const float4*)(kp + 12);
            const float* vp = Vb + (size_t)(t0 + i) * 4096 + lane * 64 + wid * 16;
            vf0 = *(const float4*)vp;       vf1 = *(const float4*)(vp + 4);
            vf2 = *(const float4*)(vp + 8); vf3 = *(const float4*)(vp + 12);
        }
    };
    auto stage_write = [&](int i) {         // cvt + swizzled LDS image write
        if (i < w) {
            u16* dst = &lsm[(i & 1) << 13];
            u16x8 a, b;
            a[0]=f2bf_rne(kf0.x); a[1]=f2bf_rne(kf0.y); a[2]=f2bf_rne(kf0.z); a[3]=f2bf_rne(kf0.w);
            a[4]=f2bf_rne(kf1.x); a[5]=f2bf_rne(kf1.y); a[6]=f2bf_rne(kf1.z); a[7]=f2bf_rne(kf1.w);
            b[0]=f2bf_rne(kf2.x); b[1]=f2bf_rne(kf2.y); b[2]=f2bf_rne(kf2.z); b[3]=f2bf_rne(kf2.w);
            b[4]=f2bf_rne(kf3.x); b[5]=f2bf_rne(kf3.y); b[6]=f2bf_rne(kf3.z); b[7]=f2bf_rne(kf3.w);
            *(u16x8*)&dst[kiA] = a;
            *(u16x8*)&dst[kiB] = b;
            float vy[16] = { vf0.x,vf0.y,vf0.z,vf0.w, vf1.x,vf1.y,vf1.z,vf1.w,
                             vf2.x,vf2.y,vf2.z,vf2.w, vf3.x,vf3.y,vf3.z,vf3.w };
            #pragma unroll
            for (int j = 0; j < 16; ++j) {
                int d = wid * 16 + j;
                dst[4096 + d * 64 + ((kc + (j & 7)) & 7) * 8 + kw] = f2bf_rne(vy[j]);
            }
        }
    };

    auto proc = [&](int kb, const u16* ls) {
        bool bdry = (kb < w_rs_max) || (kb + 64 > w_re_min);   // wave-uniform
        #pragma unroll
        for (int h = 0; h < 2; ++h) {
            int hb = h * 2048;
            // K fragments: read once, used by BOTH q-fragments
            bf16x8 k00 = *(const bf16x8*)&ls[hb + osA0];
            bf16x8 k01 = *(const bf16x8*)&ls[hb + osA1];
            bf16x8 k10 = *(const bf16x8*)&ls[hb + osA0 + 256];
            bf16x8 k11 = *(const bf16x8*)&ls[hb + osA1 + 256];
            f32x4 tA0 = {0.f,0.f,0.f,0.f}, tA1 = tA0, tB0 = tA0, tB1 = tA0;
            __builtin_amdgcn_s_setprio(1);
            tA0 = MFMA(k00, qA0, tA0); tA0 = MFMA(k01, qA1, tA0);
            tA1 = MFMA(k10, qA0, tA1); tA1 = MFMA(k11, qA1, tA1);
            tB0 = MFMA(k00, qB0, tB0); tB0 = MFMA(k01, qB1, tB0);
            tB1 = MFMA(k10, qB0, tB1); tB1 = MFMA(k11, qB1, tB1);
            __builtin_amdgcn_s_setprio(0);
            float sA[8], sB[8];
            #pragma unroll
            for (int r = 0; r < 4; ++r) {
                sA[r] = tA0[r]; sA[4 + r] = tA1[r];
                sB[r] = tB0[r]; sB[4 + r] = tB1[r];
            }
            if (bdry) {                      // boundary tiles only
                #pragma unroll
                for (int j = 0; j < 8; ++j) {
                    int key = kb + h * 32 + g * 8 + j;
                    if (key < rs_l0 || key >= re_l0) sA[j] = -1e30f;
                    if (key < rs_l1 || key >= re_l1) sB[j] = -1e30f;
                }
            }
            bf16x8 pA, pB;
            #pragma unroll
            for (int j = 0; j < 8; ++j) { float p = __builtin_amdgcn_exp2f(sA[j]); pA[j] = (short)f2bf_fast(p); }
            #pragma unroll
            for (int j = 0; j < 8; ++j) { float p = __builtin_amdgcn_exp2f(sB[j]); pB[j] = (short)f2bf_fast(p); }
            // V fragments: read once, used by BOTH q-fragments
            int ov = h ? ov1 : ov0;
            bf16x8 v0 = *(const bf16x8*)&ls[ov       ];
            bf16x8 v1 = *(const bf16x8*)&ls[ov + 1024];
            bf16x8 v2 = *(const bf16x8*)&ls[ov + 2048];
            bf16x8 v3 = *(const bf16x8*)&ls[ov + 3072];
            __builtin_amdgcn_s_setprio(1);
            accA[0] = MFMA(pA, v0, accA[0]);
            accA[1] = MFMA(pA, v1, accA[1]);
            accA[2] = MFMA(pA, v2, accA[2]);
            accA[3] = MFMA(pA, v3, accA[3]);
            acclA   = MFMA(pA, ones, acclA);
            accB[0] = MFMA(pB, v0, accB[0]);
            accB[1] = MFMA(pB, v1, accB[1]);
            accB[2] = MFMA(pB, v2, accB[2]);
            accB[3] = MFMA(pB, v3, accB[3]);
            acclB   = MFMA(pB, ones, acclB);
            __builtin_amdgcn_s_setprio(0);
        }
    };

    // prologue: tile 0 staged serially (once)
    stage_load(0);
    stage_write(0);
    for (int i = 0; i < w; ++i) {
        __syncthreads();          // buf[i&1] image complete; buf[(i+1)&1] free
        stage_load(i + 1);        // loads in flight, covered by proc(i) below
        proc(kst + (i << 6), &lsm[(i & 1) << 13]);
        stage_write(i + 1);       // vmcnt consumed here, before next barrier
    }

    // epilogue: frag A rows q0+wid*32+4g+r, frag B rows +16; cols 16c+n
    int rb = g << 2;
    {
        int orow = q0 + wid * 32 + rb;
        float* ob = O + ((size_t)bh * N + orow) * D + n;
        #pragma unroll
        for (int r = 0; r < 4; ++r) {
            float li = 1.0f / acclA[r];
            float* rp = ob + (size_t)r * D;
            rp[0]  = accA[0][r] * li;
            rp[16] = accA[1][r] * li;
            rp[32] = accA[2][r] * li;
            rp[48] = accA[3][r] * li;
        }
    }
    {
        int orow = q0 + wid * 32 + 16 + rb;
        float* ob = O + ((size_t)bh * N + orow) * D + n;
        #pragma unroll
        for (int r = 0; r < 4; ++r) {
            float li = 1.0f / acclB[r];
            float* rp = ob + (size_t)r * D;
            rp[0]  = accB[0][r] * li;
            rp[16] = accB[1][r] * li;
            rp[32] = accB[2][r] * li;
            rp[48] = accB[3][r] * li;
        }
    }
}

extern "C" void kernel_launch(void* const* d_in, const int* in_sizes, int n_in,
                              void* d_out, int out_size, void* d_ws, size_t ws_size,
                              hipStream_t stream) {
    const float* q  = (const float*)d_in[0];
    const float* k  = (const float*)d_in[1];
    const float* v  = (const float*)d_in[2];
    const float* sc = (const float*)d_in[3];
    const int* rs   = (const int*)d_in[4];
    const int* re   = (const int*)d_in[5];
    float* out      = (float*)d_out;

    bsattn_fused<<<dim3(512), dim3(256), 0, stream>>>(q, k, v, sc, rs, re, out);
}